// Round 19
// baseline (324.130 us; speedup 1.0000x reference)
//
#include <hip/hip_runtime.h>
#include <hip/hip_bf16.h>
#include <stdint.h>
#include <stddef.h>

typedef __bf16 bf16_t;
typedef __attribute__((ext_vector_type(8))) __bf16 bf16x8;
typedef __attribute__((ext_vector_type(4))) __bf16 bf16x4;
typedef __attribute__((ext_vector_type(4))) float f32x4;
typedef __attribute__((ext_vector_type(4))) int i32x4;
typedef __attribute__((ext_vector_type(16))) char c8x16;

#define M_DIM 32768
#define N_DIM 4096
#define K_DIM 1024
#define NT 8  // K / 128

static __device__ __forceinline__ void gload16(const void* g, void* s) {
  __builtin_amdgcn_global_load_lds(
      (const __attribute__((address_space(1))) void*)g,
      (__attribute__((address_space(3))) void*)s,
      16, 0, 0);
}

// -------- x: fp32 [M][K] -> int8 [M][K] + per-row scale (absmax/127) ------
__global__ void quant_x_kernel(const float* __restrict__ x,
                               int8_t* __restrict__ xq,
                               float* __restrict__ xs) {
  const int row = blockIdx.x * 4 + (threadIdx.x >> 6);  // 1 wave / row
  const int lane = threadIdx.x & 63;
  const float* src = x + (long)row * K_DIM + lane * 16;
  float4 v[4];
#pragma unroll
  for (int i = 0; i < 4; ++i) v[i] = ((const float4*)src)[i];
  float am = 0.f;
#pragma unroll
  for (int i = 0; i < 4; ++i) {
    am = fmaxf(am, fmaxf(fmaxf(fabsf(v[i].x), fabsf(v[i].y)),
                         fmaxf(fabsf(v[i].z), fabsf(v[i].w))));
  }
#pragma unroll
  for (int off = 32; off; off >>= 1) am = fmaxf(am, __shfl_xor(am, off));
  const float sq = am > 0.f ? 127.f / am : 0.f;
  c8x16 q;
#pragma unroll
  for (int i = 0; i < 4; ++i) {
    const float* f = (const float*)&v[i];
#pragma unroll
    for (int j = 0; j < 4; ++j) {
      int qi = (int)rintf(f[j] * sq);
      qi = qi > 127 ? 127 : (qi < -127 ? -127 : qi);
      q[i * 4 + j] = (char)qi;
    }
  }
  *(c8x16*)(xq + (long)row * K_DIM + lane * 16) = q;
  if (lane == 0) xs[row] = am * (1.f / 127.f);
}

// -------- w: int32 [K][N] -> int8 Wq [N][K] (exact, values in [-127,127]) -
__global__ void cvt_w_i8_kernel(const int* __restrict__ qw,
                                int8_t* __restrict__ wq) {
  __shared__ char t[64][80];
  const int bk = blockIdx.x & 15;
  const int bn = blockIdx.x >> 4;
  const int k0 = bk * 64, n0 = bn * 64;
  const int tid = threadIdx.x;
  {
    const int kl = tid >> 2;
    const int nc = (tid & 3) * 16;
    const int* src = qw + (long)(k0 + kl) * N_DIM + n0 + nc;
#pragma unroll
    for (int c = 0; c < 4; ++c) {
      i32x4 v = *(const i32x4*)(src + c * 4);
#pragma unroll
      for (int j = 0; j < 4; ++j) t[nc + c * 4 + j][kl] = (char)v[j];
    }
  }
  __syncthreads();
  {
    const int nl = tid >> 2;
    const int kc = (tid & 3) * 16;
    *(i32x4*)(wq + (long)(n0 + nl) * K_DIM + k0 + kc) =
        *(const i32x4*)&t[nl][kc];
  }
}

// ---- i8 GEMM 128x128, BK=128, 4 waves, 3 blocks/CU, B direct-from-global -
// r18 (replay-verified) was LDS-BW-bound (~100% of 112B/cy incl. staged
// writes). Change: B fragments load global->register (B panel 512KB/XCD is
// L2-resident; per-tile slice 16KB; per (n,kk) a wave gathers 16 full 64B
// lines). LDS holds ONLY A -- r18's A layout/swizzle verbatim (0 conflicts):
//  A region h (8KB, 64 slots x 128B): rows {h*32+[0,32)} u {64+h*32+[0,32)}
//    slot s -> row h*32 + (s>>5)*64 + (s&31); frag m: region m>>1,
//    slot wm*32 + (m&1)*16 + lr.  Swizzle: LDS(slot,c16) = chunk c^(slot&7);
//    readers ck = ((kk*4+lg) ^ (lr&7))<<4.
// LDS = 2 bufs x 16KB = 32KB -> 3 blocks/CU; LDS traffic halved.
// Schedule: 2 phases/tile. A-only queue (4 loads):
//  P1: vmcnt(2)+bar -> lands Ah0(t) [in-order retirement: older B loads
//      also landed]; B loads (8); stage Ah0(t+1); read A01; 16 MFMA.
//  P2: vmcnt(2)+bar -> lands Ah1(t) [leaves Ah0(t+1)]; stage Ah1(t+1);
//      read A23; 16 MFMA.   Tail: 2 / 0.
// WAR: stage into nb at Pk(t); nb's region read at Pk(t-1), >=2 barriers
// earlier. Waits ALWAYS precede the reads they guard (r7 lesson).
__global__ __launch_bounds__(256, 3) void gemm_i8_kernel(
    const int8_t* __restrict__ Aq, const int8_t* __restrict__ Bq,
    const float* __restrict__ xs, const float* __restrict__ scale_p,
    const float* __restrict__ bias, float* __restrict__ C) {
  __shared__ __align__(16) char lds[32768];  // 2 bufs x 16KB (A only)

  // XCD ownership (bijective; nwg = 8192): XCD x owns tn {4x..4x+3}; tnl
  // fastest so consecutive blocks share one A-tile; all XCDs sweep the same
  // tm window (A served via LLC); B panel stays hot in the XCD's L2.
  const int xcd = blockIdx.x & 7;
  const int slot = blockIdx.x >> 3;        // 0..1023
  const int tn = (xcd << 2) | (slot & 3);  // 0..31
  const int tm = slot >> 2;                // 0..255

  const int tid = threadIdx.x;
  const int wave = tid >> 6;  // 0..3
  const int lane = tid & 63;
  const int lr = lane & 15;
  const int lg = lane >> 4;
  const int wm = wave >> 1;  // 0..1
  const int wn = wave & 1;   // 0..1

  const long aRow0 = (long)tm * 128;
  const long bRow0 = (long)tn * 128;

  // A staging: issue = 4KB = 32 slots x 128B; thread covers slot s = tid>>3,
  // source 16B chunk pre-swizzled by s&7 (gload_lds dest stays linear)
  const int s = tid >> 3;
  const int scol = ((tid & 7) ^ (s & 7)) * 16;
  const int8_t* aS = Aq + (aRow0 + s) * K_DIM + scol;
  char* sBase = lds + wave * 1024;

  // buf b (16KB): region h at b*16384 + h*8192
#define STG_A(b, h, t)                                                      \
  do {                                                                      \
    gload16(aS + (long)((h) * 32) * K_DIM + (t) * 128,                      \
            sBase + (b) * 16384 + (h) * 8192);                              \
    gload16(aS + (long)((h) * 32 + 64) * K_DIM + (t) * 128,                 \
            sBase + (b) * 16384 + (h) * 8192 + 4096);                       \
  } while (0)

  const int ck0 = ((0 + lg) ^ (lr & 7)) << 4;
  const int ck1 = ((4 + lg) ^ (lr & 7)) << 4;

#define LDA(m, kk)                                                           \
  (*(const i32x4*)(lds + bb + ((m) >> 1) * 8192 +                            \
                   (wm * 32 + ((m) & 1) * 16 + lr) * 128 +                   \
                   ((kk) ? ck1 : ck0)))

  // B direct: lane reads Wq[bRow0 + wn*64 + n*16 + lr][t*128 + kk*64 + lg*16]
  const int8_t* bP = Bq + (bRow0 + wn * 64 + lr) * (long)K_DIM + lg * 16;
#define LDB_G(n, kk, t) \
  (*(const i32x4*)(bP + (long)(n) * 16 * K_DIM + (t) * 128 + (kk) * 64))

#define SYNC(Nimm)                                           \
  do {                                                       \
    asm volatile("s_waitcnt vmcnt(" #Nimm ")" ::: "memory"); \
    __builtin_amdgcn_s_barrier();                            \
    __builtin_amdgcn_sched_barrier(0);                       \
  } while (0)

  i32x4 acc[4][4] = {};
  i32x4 bfr[4][2], afr[2][2];

#define MFMA_ROWS(mbase)                                                      \
  do {                                                                        \
    __builtin_amdgcn_s_setprio(1);                                            \
    _Pragma("unroll") for (int mm = 0; mm < 2; ++mm)                          \
    _Pragma("unroll") for (int nn = 0; nn < 4; ++nn)                          \
    _Pragma("unroll") for (int kk = 0; kk < 2; ++kk)                          \
      acc[(mbase) + mm][nn] = __builtin_amdgcn_mfma_i32_16x16x64_i8(          \
          afr[mm][kk], bfr[nn][kk], acc[(mbase) + mm][nn], 0, 0, 0);          \
    __builtin_amdgcn_s_setprio(0);                                            \
  } while (0)

#define RD_B(t)                                                               \
  _Pragma("unroll") for (int n = 0; n < 4; ++n) {                             \
    bfr[n][0] = LDB_G(n, 0, t);                                               \
    bfr[n][1] = LDB_G(n, 1, t);                                               \
  }
#define RD_A01()                                                              \
  _Pragma("unroll") for (int mm = 0; mm < 2; ++mm) {                          \
    afr[mm][0] = LDA(mm, 0);                                                  \
    afr[mm][1] = LDA(mm, 1);                                                  \
  }
#define RD_A23()                                                              \
  _Pragma("unroll") for (int mm = 0; mm < 2; ++mm) {                          \
    afr[mm][0] = LDA(mm + 2, 0);                                              \
    afr[mm][1] = LDA(mm + 2, 1);                                              \
  }

  // prologue: tile 0's two A halves (queue = [Ah0(2), Ah1(2)])
  STG_A(0, 0, 0);
  STG_A(0, 1, 0);

#pragma unroll 1
  for (int t = 0; t < NT - 1; ++t) {
    const int b = t & 1;
    const int nb = b ^ 1;
    const int bb = b * 16384;
    // P1: lands Ah0(t) (leaves Ah1(t))
    SYNC(2);
    RD_B(t);
    STG_A(nb, 0, t + 1);
    RD_A01();
    MFMA_ROWS(0);
    // P2: lands Ah1(t) (leaves Ah0(t+1))
    SYNC(2);
    STG_A(nb, 1, t + 1);
    RD_A23();
    MFMA_ROWS(2);
  }
  {  // tail t = NT-1 (odd -> buf 1); queue = [Ah0,Ah1], no staging
    const int bb = 16384;
    SYNC(2);
    RD_B(NT - 1);
    RD_A01();
    MFMA_ROWS(0);
    SYNC(0);
    RD_A23();
    MFMA_ROWS(2);
  }

#undef STG_A
#undef LDA
#undef LDB_G
#undef SYNC
#undef MFMA_ROWS
#undef RD_B
#undef RD_A01
#undef RD_A23

  // epilogue (r15/r18-verified): C/D col = lane&15, row = (lane>>4)*4 + reg
  // out = i32acc * (xs[row] * wscale) + bias[col]
  const float ws = *scale_p;
  const int col_base = (tn << 7) + wn * 64;
  const int row_base = (tm << 7) + wm * 64 + lg * 4;
  float4 svw[4];
#pragma unroll
  for (int m = 0; m < 4; ++m) {
    float4 sv = *(const float4*)(xs + row_base + m * 16);
    svw[m].x = sv.x * ws; svw[m].y = sv.y * ws;
    svw[m].z = sv.z * ws; svw[m].w = sv.w * ws;
  }
#pragma unroll
  for (int n = 0; n < 4; ++n) {
    const int col = col_base + n * 16 + lr;
    const float bv = bias[col];
#pragma unroll
    for (int m = 0; m < 4; ++m) {
      float* cp = C + (long)(row_base + m * 16) * N_DIM + col;
      const float* sw = (const float*)&svw[m];
#pragma unroll
      for (int j = 0; j < 4; ++j)
        __builtin_nontemporal_store((float)acc[m][n][j] * sw[j] + bv,
                                    cp + (long)j * N_DIM);
    }
  }
}

// ---------------- fallback (ws too small): bf16 reg-staged 128^2 ----------
__global__ void cvt_w_kernel(const int* __restrict__ qw, bf16_t* __restrict__ wt) {
  __shared__ bf16_t t[64][72];
  const int bk = blockIdx.x & 15;
  const int bn = blockIdx.x >> 4;
  const int k0 = bk * 64, n0 = bn * 64;
  const int tid = threadIdx.x;
  {
    const int kl = tid >> 2;
    const int nc = (tid & 3) * 16;
    const int* src = qw + (long)(k0 + kl) * N_DIM + n0 + nc;
#pragma unroll
    for (int c = 0; c < 4; ++c) {
      i32x4 v = *(const i32x4*)(src + c * 4);
#pragma unroll
      for (int j = 0; j < 4; ++j)
        t[nc + c * 4 + j][kl] = (bf16_t)(float)v[j];
    }
  }
  __syncthreads();
  {
    const int nl = tid >> 2;
    const int kc = (tid & 3) * 16;
    bf16_t* dst = wt + (long)(n0 + nl) * K_DIM + k0 + kc;
#pragma unroll
    for (int j = 0; j < 16; ++j) dst[j] = t[nl][kc + j];
  }
}

__global__ __launch_bounds__(256, 2) void gemm_fb_kernel(
    const float* __restrict__ Af, const bf16_t* __restrict__ Bt,
    const float* __restrict__ scale_p, const float* __restrict__ bias,
    float* __restrict__ C) {
  __shared__ bf16_t lA[128][64];
  __shared__ bf16_t lB[128][64];
  const int nwg = gridDim.x;
  int wg = blockIdx.x;
  wg = (wg & 7) * (nwg >> 3) + (wg >> 3);
  const int tm = wg & 255;
  const int tn = wg >> 8;
  const int tid = threadIdx.x;
  const int wave = tid >> 6;
  const int lane = tid & 63;
  const int lr = lane & 15;
  const int lg = lane >> 4;
  const int wm = wave >> 1;
  const int wn = wave & 1;
  const long aRow0 = (long)tm * 128;
  const long bRow0 = (long)tn * 128;
  const bf16_t* bSrc = Bt + (bRow0 + (tid >> 3)) * K_DIM + (tid & 7) * 8;
  char* ldsB = (char*)&lB[0][0] + wave * 1024;
  f32x4 acc[4][4] = {};
  for (int k0 = 0; k0 < K_DIM; k0 += 64) {
    __syncthreads();
#pragma unroll
    for (int j = 0; j < 8; ++j) {
      const int e = j * 1024 + tid * 4;
      const int row = e >> 6;
      const int col = e & 63;
      float4 v = *(const float4*)(Af + (aRow0 + row) * K_DIM + k0 + col);
      bf16x4 o;
      o[0] = (__bf16)v.x; o[1] = (__bf16)v.y; o[2] = (__bf16)v.z; o[3] = (__bf16)v.w;
      *(bf16x4*)((char*)&lA[0][0] + (size_t)e * 2) = o;
    }
#pragma unroll
    for (int i = 0; i < 4; ++i)
      gload16(bSrc + (long)i * 32 * K_DIM + k0, ldsB + i * 4096);
    __syncthreads();
#pragma unroll
    for (int kk = 0; kk < 2; ++kk) {
      bf16x8 af[4], bg[4];
#pragma unroll
      for (int m = 0; m < 4; ++m)
        af[m] = *(const bf16x8*)&lA[wm * 64 + m * 16 + lr][kk * 32 + lg * 8];
#pragma unroll
      for (int n = 0; n < 4; ++n)
        bg[n] = *(const bf16x8*)&lB[wn * 64 + n * 16 + lr][kk * 32 + lg * 8];
#pragma unroll
      for (int m = 0; m < 4; ++m)
#pragma unroll
        for (int n = 0; n < 4; ++n)
          acc[m][n] = __builtin_amdgcn_mfma_f32_16x16x32_bf16(af[m], bg[n], acc[m][n], 0, 0, 0);
    }
  }
  const float s = *scale_p;
  const int col0 = (tn << 7) + wn * 64;
  const int row0 = (tm << 7) + wm * 64 + lg * 4;
#pragma unroll
  for (int n = 0; n < 4; ++n) {
    const int col = col0 + n * 16 + lr;
    const float bv = bias[col];
#pragma unroll
    for (int m = 0; m < 4; ++m) {
      float* cp = C + (long)(row0 + m * 16) * N_DIM + col;
#pragma unroll
      for (int j = 0; j < 4; ++j)
        cp[(long)j * N_DIM] = acc[m][n][j] * s + bv;
    }
  }
}

extern "C" void kernel_launch(void* const* d_in, const int* in_sizes, int n_in,
                              void* d_out, int out_size, void* d_ws, size_t ws_size,
                              hipStream_t stream) {
  const float* x = (const float*)d_in[0];
  const int* qw = (const int*)d_in[1];  // harness pushes ints as int32
  const float* scale = (const float*)d_in[2];
  const float* bias = (const float*)d_in[3];
  float* out = (float*)d_out;

  // i8-path workspace: Wq 4MB | xs 256KB | Xq 32MB
  const size_t wq_bytes = (size_t)N_DIM * K_DIM;          // 4 MB
  const size_t xs_off = wq_bytes;                         // 4 MB
  const size_t xq_off = wq_bytes + (256u << 10);          // 4.25 MB
  const size_t need = xq_off + (size_t)M_DIM * K_DIM;     // ~36.25 MB

  if (ws_size >= need) {
    int8_t* wq = (int8_t*)d_ws;
    float* xs = (float*)((char*)d_ws + xs_off);
    int8_t* xq = (int8_t*)((char*)d_ws + xq_off);
    cvt_w_i8_kernel<<<dim3((K_DIM / 64) * (N_DIM / 64)), dim3(256), 0, stream>>>(qw, wq);
    quant_x_kernel<<<dim3(M_DIM / 4), dim3(256), 0, stream>>>(x, xq, xs);
    gemm_i8_kernel<<<dim3((M_DIM / 128) * (N_DIM / 128)), dim3(256), 0, stream>>>(
        xq, wq, xs, scale, bias, out);
  } else {
    bf16_t* wt = (bf16_t*)d_ws;  // 8 MB
    cvt_w_kernel<<<dim3((K_DIM / 64) * (N_DIM / 64)), dim3(256), 0, stream>>>(qw, wt);
    gemm_fb_kernel<<<dim3((M_DIM / 128) * (N_DIM / 128)), dim3(256), 0, stream>>>(
        x, wt, scale, bias, out);
  }
}

// Round 20
// 210.314 us; speedup vs baseline: 1.5412x; 1.5412x over previous
//
#include <hip/hip_runtime.h>
#include <hip/hip_bf16.h>
#include <stdint.h>
#include <stddef.h>

typedef __bf16 bf16_t;
typedef __attribute__((ext_vector_type(8))) __bf16 bf16x8;
typedef __attribute__((ext_vector_type(4))) __bf16 bf16x4;
typedef __attribute__((ext_vector_type(4))) float f32x4;
typedef __attribute__((ext_vector_type(4))) int i32x4;
typedef __attribute__((ext_vector_type(16))) char c8x16;

#define M_DIM 32768
#define N_DIM 4096
#define K_DIM 1024
#define NT 8  // K / 128

static __device__ __forceinline__ void gload16(const void* g, void* s) {
  __builtin_amdgcn_global_load_lds(
      (const __attribute__((address_space(1))) void*)g,
      (__attribute__((address_space(3))) void*)s,
      16, 0, 0);
}

// -------- x: fp32 [M][K] -> int8 [M][K] + per-row scale (absmax/127) ------
__global__ void quant_x_kernel(const float* __restrict__ x,
                               int8_t* __restrict__ xq,
                               float* __restrict__ xs) {
  const int row = blockIdx.x * 4 + (threadIdx.x >> 6);  // 1 wave / row
  const int lane = threadIdx.x & 63;
  const float* src = x + (long)row * K_DIM + lane * 16;
  float4 v[4];
#pragma unroll
  for (int i = 0; i < 4; ++i) v[i] = ((const float4*)src)[i];
  float am = 0.f;
#pragma unroll
  for (int i = 0; i < 4; ++i) {
    am = fmaxf(am, fmaxf(fmaxf(fabsf(v[i].x), fabsf(v[i].y)),
                         fmaxf(fabsf(v[i].z), fabsf(v[i].w))));
  }
#pragma unroll
  for (int off = 32; off; off >>= 1) am = fmaxf(am, __shfl_xor(am, off));
  const float sq = am > 0.f ? 127.f / am : 0.f;
  c8x16 q;
#pragma unroll
  for (int i = 0; i < 4; ++i) {
    const float* f = (const float*)&v[i];
#pragma unroll
    for (int j = 0; j < 4; ++j) {
      int qi = (int)rintf(f[j] * sq);
      qi = qi > 127 ? 127 : (qi < -127 ? -127 : qi);
      q[i * 4 + j] = (char)qi;
    }
  }
  *(c8x16*)(xq + (long)row * K_DIM + lane * 16) = q;
  if (lane == 0) xs[row] = am * (1.f / 127.f);
}

// -------- w: int32 [K][N] -> int8 Wq [N][K] (exact, values in [-127,127]) -
__global__ void cvt_w_i8_kernel(const int* __restrict__ qw,
                                int8_t* __restrict__ wq) {
  __shared__ char t[64][80];
  const int bk = blockIdx.x & 15;
  const int bn = blockIdx.x >> 4;
  const int k0 = bk * 64, n0 = bn * 64;
  const int tid = threadIdx.x;
  {
    const int kl = tid >> 2;
    const int nc = (tid & 3) * 16;
    const int* src = qw + (long)(k0 + kl) * N_DIM + n0 + nc;
#pragma unroll
    for (int c = 0; c < 4; ++c) {
      i32x4 v = *(const i32x4*)(src + c * 4);
#pragma unroll
      for (int j = 0; j < 4; ++j) t[nc + c * 4 + j][kl] = (char)v[j];
    }
  }
  __syncthreads();
  {
    const int nl = tid >> 2;
    const int kc = (tid & 3) * 16;
    *(i32x4*)(wq + (long)(n0 + nl) * K_DIM + k0 + kc) =
        *(const i32x4*)&t[nl][kc];
  }
}

// ------- i8 GEMM 128x128, BK=128, 4 waves, 2 blocks/CU, 2 syncs/tile ------
// HYBRID of two replay-verified kernels: r18's i8/BK=128 geometry (layout,
// swizzle, staging, epilogue byte-identical) on r9's 2-sync-per-tile
// schedule (16 sync points total vs r18's 24 -- sync count is the proven
// lever: r16->r18 48->24 points = -21us).
// Geometry (r18): A region h (8KB, 64 slots x 128B): rows {h*32+[0,32)} u
// {64+h*32+[0,32)}; slot s -> row h*32+(s>>5)*64+(s&31); frag m: region
// m>>1, slot wm*32+(m&1)*16+lr. B identical with wn,n. Swizzle (verified
// 0-conflict): LDS(slot,c16) = chunk c^(slot&7); readers
// ck = ((kk*4+lg)^(lr&7))<<4.
// Schedule (r9): prologue stages [Ah0,Bh0,Bh1,Ah1](0) (8 loads). Per tile:
//  P1: SYNC(2) lands {Ah0,Bh0,Bh1}(t); read B-all + A01 (12 b128);
//      stage Ah0(t+1), Bh0(t+1); MFMA 16 (rows m0-1).
//  P2: SYNC(4) lands Ah1(t); read A23; stage Bh1(t+1), Ah1(t+1);
//      MFMA 16 (rows m2-3).   Tail: SYNC(2) then SYNC(0).
// Queue audit = r9's verbatim (steady 8 -> 6 -> 8). WAR: each region's
// last read retires (lgkm before consuming MFMA) >=2 barriers before its
// overwrite. Waits ALWAYS precede the reads they guard (r7 lesson).
__global__ __launch_bounds__(256, 2) void gemm_i8_kernel(
    const int8_t* __restrict__ Aq, const int8_t* __restrict__ Bq,
    const float* __restrict__ xs, const float* __restrict__ scale_p,
    const float* __restrict__ bias, float* __restrict__ C) {
  __shared__ __align__(16) char lds[65536];  // 2 bufs x (A 16KB + B 16KB)

  // XCD ownership (bijective; nwg = 8192): XCD x owns tn {4x..4x+3}; tnl
  // fastest so consecutive blocks share one A-tile; all XCDs sweep the same
  // tm window (A served via LLC).
  const int xcd = blockIdx.x & 7;
  const int slot = blockIdx.x >> 3;        // 0..1023
  const int tn = (xcd << 2) | (slot & 3);  // 0..31
  const int tm = slot >> 2;                // 0..255

  const int tid = threadIdx.x;
  const int wave = tid >> 6;  // 0..3
  const int lane = tid & 63;
  const int lr = lane & 15;
  const int lg = lane >> 4;
  const int wm = wave >> 1;  // 0..1
  const int wn = wave & 1;   // 0..1

  const long aRow0 = (long)tm * 128;
  const long bRow0 = (long)tn * 128;

  // staging: issue = 4KB = 32 slots x 128B; thread covers slot s = tid>>3,
  // source 16B chunk pre-swizzled by s&7 (gload_lds dest stays linear)
  const int s = tid >> 3;
  const int scol = ((tid & 7) ^ (s & 7)) * 16;  // i8 elems == bytes
  const int8_t* aS = Aq + (aRow0 + s) * K_DIM + scol;
  const int8_t* bS = Bq + (bRow0 + s) * K_DIM + scol;
  char* sBase = lds + wave * 1024;

  // buf b (32KB): A regions at b*32768 + h*8192; B at b*32768+16384 + h*8192
#define STG_A(b, h, t)                                                      \
  do {                                                                      \
    gload16(aS + (long)((h) * 32) * K_DIM + (t) * 128,                      \
            sBase + (b) * 32768 + (h) * 8192);                              \
    gload16(aS + (long)((h) * 32 + 64) * K_DIM + (t) * 128,                 \
            sBase + (b) * 32768 + (h) * 8192 + 4096);                       \
  } while (0)
#define STG_B(b, h, t)                                                      \
  do {                                                                      \
    gload16(bS + (long)((h) * 32) * K_DIM + (t) * 128,                      \
            sBase + (b) * 32768 + 16384 + (h) * 8192);                      \
    gload16(bS + (long)((h) * 32 + 64) * K_DIM + (t) * 128,                 \
            sBase + (b) * 32768 + 16384 + (h) * 8192 + 4096);               \
  } while (0)

  const int ck0 = ((0 + lg) ^ (lr & 7)) << 4;
  const int ck1 = ((4 + lg) ^ (lr & 7)) << 4;

#define LDA(m, kk)                                                           \
  (*(const i32x4*)(lds + bb + ((m) >> 1) * 8192 +                            \
                   (wm * 32 + ((m) & 1) * 16 + lr) * 128 +                   \
                   ((kk) ? ck1 : ck0)))
#define LDB(n, kk)                                                           \
  (*(const i32x4*)(lds + bb + 16384 + ((n) >> 1) * 8192 +                    \
                   (wn * 32 + ((n) & 1) * 16 + lr) * 128 +                   \
                   ((kk) ? ck1 : ck0)))

#define SYNC(Nimm)                                           \
  do {                                                       \
    asm volatile("s_waitcnt vmcnt(" #Nimm ")" ::: "memory"); \
    __builtin_amdgcn_s_barrier();                            \
    __builtin_amdgcn_sched_barrier(0);                       \
  } while (0)

  i32x4 acc[4][4] = {};
  i32x4 bfr[4][2], afr[2][2];

#define MFMA_Q(mbase, nbase)                                                  \
  do {                                                                        \
    __builtin_amdgcn_s_setprio(1);                                            \
    _Pragma("unroll") for (int mm = 0; mm < 2; ++mm)                          \
    _Pragma("unroll") for (int nn = 0; nn < 2; ++nn)                          \
    _Pragma("unroll") for (int kk = 0; kk < 2; ++kk)                          \
      acc[(mbase) + mm][(nbase) + nn] =                                       \
          __builtin_amdgcn_mfma_i32_16x16x64_i8(                              \
              afr[mm][kk], bfr[(nbase) + nn][kk],                             \
              acc[(mbase) + mm][(nbase) + nn], 0, 0, 0);                      \
    __builtin_amdgcn_s_setprio(0);                                            \
  } while (0)

#define RD_B_ALL()                                                            \
  _Pragma("unroll") for (int n = 0; n < 4; ++n) {                             \
    bfr[n][0] = LDB(n, 0);                                                    \
    bfr[n][1] = LDB(n, 1);                                                    \
  }
#define RD_A01()                                                              \
  _Pragma("unroll") for (int mm = 0; mm < 2; ++mm) {                          \
    afr[mm][0] = LDA(mm, 0);                                                  \
    afr[mm][1] = LDA(mm, 1);                                                  \
  }
#define RD_A23()                                                              \
  _Pragma("unroll") for (int mm = 0; mm < 2; ++mm) {                          \
    afr[mm][0] = LDA(mm + 2, 0);                                              \
    afr[mm][1] = LDA(mm + 2, 1);                                              \
  }

  // prologue: tile 0 in order Ah0, Bh0, Bh1, Ah1 (8 loads)
  STG_A(0, 0, 0);
  STG_B(0, 0, 0);
  STG_B(0, 1, 0);
  STG_A(0, 1, 0);

#pragma unroll 1
  for (int t = 0; t < NT - 1; ++t) {
    const int b = t & 1;
    const int nb = b ^ 1;
    const int bb = b * 32768;
    // P1: SYNC(2) lands {Ah0,Bh0,Bh1}(t); Ah1(t) still in flight
    SYNC(2);
    RD_B_ALL();
    RD_A01();
    STG_A(nb, 0, t + 1);
    STG_B(nb, 0, t + 1);
    MFMA_Q(0, 0);
    MFMA_Q(0, 2);
    // P2: SYNC(4) lands Ah1(t); {Ah0',Bh0'} stay in flight
    SYNC(4);
    RD_A23();
    STG_B(nb, 1, t + 1);
    STG_A(nb, 1, t + 1);
    MFMA_Q(2, 0);
    MFMA_Q(2, 2);
  }
  {  // tail t = NT-1 (odd -> buf 1); entering queue = 8, no staging
    const int bb = 32768;
    SYNC(2);
    RD_B_ALL();
    RD_A01();
    MFMA_Q(0, 0);
    MFMA_Q(0, 2);
    SYNC(0);
    RD_A23();
    MFMA_Q(2, 0);
    MFMA_Q(2, 2);
  }

#undef STG_A
#undef STG_B
#undef LDA
#undef LDB
#undef SYNC
#undef MFMA_Q
#undef RD_B_ALL
#undef RD_A01
#undef RD_A23

  // epilogue (r15/r18-verified): C/D col = lane&15, row = (lane>>4)*4 + reg
  // out = i32acc * (xs[row] * wscale) + bias[col]
  const float ws = *scale_p;
  const int col_base = (tn << 7) + wn * 64;
  const int row_base = (tm << 7) + wm * 64 + lg * 4;
  float4 svw[4];
#pragma unroll
  for (int m = 0; m < 4; ++m) {
    float4 sv = *(const float4*)(xs + row_base + m * 16);
    svw[m].x = sv.x * ws; svw[m].y = sv.y * ws;
    svw[m].z = sv.z * ws; svw[m].w = sv.w * ws;
  }
#pragma unroll
  for (int n = 0; n < 4; ++n) {
    const int col = col_base + n * 16 + lr;
    const float bv = bias[col];
#pragma unroll
    for (int m = 0; m < 4; ++m) {
      float* cp = C + (long)(row_base + m * 16) * N_DIM + col;
      const float* sw = (const float*)&svw[m];
#pragma unroll
      for (int j = 0; j < 4; ++j)
        __builtin_nontemporal_store((float)acc[m][n][j] * sw[j] + bv,
                                    cp + (long)j * N_DIM);
    }
  }
}

// ---------------- fallback (ws too small): bf16 reg-staged 128^2 ----------
__global__ void cvt_w_kernel(const int* __restrict__ qw, bf16_t* __restrict__ wt) {
  __shared__ bf16_t t[64][72];
  const int bk = blockIdx.x & 15;
  const int bn = blockIdx.x >> 4;
  const int k0 = bk * 64, n0 = bn * 64;
  const int tid = threadIdx.x;
  {
    const int kl = tid >> 2;
    const int nc = (tid & 3) * 16;
    const int* src = qw + (long)(k0 + kl) * N_DIM + n0 + nc;
#pragma unroll
    for (int c = 0; c < 4; ++c) {
      i32x4 v = *(const i32x4*)(src + c * 4);
#pragma unroll
      for (int j = 0; j < 4; ++j)
        t[nc + c * 4 + j][kl] = (bf16_t)(float)v[j];
    }
  }
  __syncthreads();
  {
    const int nl = tid >> 2;
    const int kc = (tid & 3) * 16;
    bf16_t* dst = wt + (long)(n0 + nl) * K_DIM + k0 + kc;
#pragma unroll
    for (int j = 0; j < 16; ++j) dst[j] = t[nl][kc + j];
  }
}

__global__ __launch_bounds__(256, 2) void gemm_fb_kernel(
    const float* __restrict__ Af, const bf16_t* __restrict__ Bt,
    const float* __restrict__ scale_p, const float* __restrict__ bias,
    float* __restrict__ C) {
  __shared__ bf16_t lA[128][64];
  __shared__ bf16_t lB[128][64];
  const int nwg = gridDim.x;
  int wg = blockIdx.x;
  wg = (wg & 7) * (nwg >> 3) + (wg >> 3);
  const int tm = wg & 255;
  const int tn = wg >> 8;
  const int tid = threadIdx.x;
  const int wave = tid >> 6;
  const int lane = tid & 63;
  const int lr = lane & 15;
  const int lg = lane >> 4;
  const int wm = wave >> 1;
  const int wn = wave & 1;
  const long aRow0 = (long)tm * 128;
  const long bRow0 = (long)tn * 128;
  const bf16_t* bSrc = Bt + (bRow0 + (tid >> 3)) * K_DIM + (tid & 7) * 8;
  char* ldsB = (char*)&lB[0][0] + wave * 1024;
  f32x4 acc[4][4] = {};
  for (int k0 = 0; k0 < K_DIM; k0 += 64) {
    __syncthreads();
#pragma unroll
    for (int j = 0; j < 8; ++j) {
      const int e = j * 1024 + tid * 4;
      const int row = e >> 6;
      const int col = e & 63;
      float4 v = *(const float4*)(Af + (aRow0 + row) * K_DIM + k0 + col);
      bf16x4 o;
      o[0] = (__bf16)v.x; o[1] = (__bf16)v.y; o[2] = (__bf16)v.z; o[3] = (__bf16)v.w;
      *(bf16x4*)((char*)&lA[0][0] + (size_t)e * 2) = o;
    }
#pragma unroll
    for (int i = 0; i < 4; ++i)
      gload16(bSrc + (long)i * 32 * K_DIM + k0, ldsB + i * 4096);
    __syncthreads();
#pragma unroll
    for (int kk = 0; kk < 2; ++kk) {
      bf16x8 af[4], bg[4];
#pragma unroll
      for (int m = 0; m < 4; ++m)
        af[m] = *(const bf16x8*)&lA[wm * 64 + m * 16 + lr][kk * 32 + lg * 8];
#pragma unroll
      for (int n = 0; n < 4; ++n)
        bg[n] = *(const bf16x8*)&lB[wn * 64 + n * 16 + lr][kk * 32 + lg * 8];
#pragma unroll
      for (int m = 0; m < 4; ++m)
#pragma unroll
        for (int n = 0; n < 4; ++n)
          acc[m][n] = __builtin_amdgcn_mfma_f32_16x16x32_bf16(af[m], bg[n], acc[m][n], 0, 0, 0);
    }
  }
  const float s = *scale_p;
  const int col0 = (tn << 7) + wn * 64;
  const int row0 = (tm << 7) + wm * 64 + lg * 4;
#pragma unroll
  for (int n = 0; n < 4; ++n) {
    const int col = col0 + n * 16 + lr;
    const float bv = bias[col];
#pragma unroll
    for (int m = 0; m < 4; ++m) {
      float* cp = C + (long)(row0 + m * 16) * N_DIM + col;
#pragma unroll
      for (int j = 0; j < 4; ++j)
        cp[(long)j * N_DIM] = acc[m][n][j] * s + bv;
    }
  }
}

extern "C" void kernel_launch(void* const* d_in, const int* in_sizes, int n_in,
                              void* d_out, int out_size, void* d_ws, size_t ws_size,
                              hipStream_t stream) {
  const float* x = (const float*)d_in[0];
  const int* qw = (const int*)d_in[1];  // harness pushes ints as int32
  const float* scale = (const float*)d_in[2];
  const float* bias = (const float*)d_in[3];
  float* out = (float*)d_out;

  // i8-path workspace: Wq 4MB | xs 256KB | Xq 32MB
  const size_t wq_bytes = (size_t)N_DIM * K_DIM;          // 4 MB
  const size_t xs_off = wq_bytes;                         // 4 MB
  const size_t xq_off = wq_bytes + (256u << 10);          // 4.25 MB
  const size_t need = xq_off + (size_t)M_DIM * K_DIM;     // ~36.25 MB

  if (ws_size >= need) {
    int8_t* wq = (int8_t*)d_ws;
    float* xs = (float*)((char*)d_ws + xs_off);
    int8_t* xq = (int8_t*)((char*)d_ws + xq_off);
    cvt_w_i8_kernel<<<dim3((K_DIM / 64) * (N_DIM / 64)), dim3(256), 0, stream>>>(qw, wq);
    quant_x_kernel<<<dim3(M_DIM / 4), dim3(256), 0, stream>>>(x, xq, xs);
    gemm_i8_kernel<<<dim3((M_DIM / 128) * (N_DIM / 128)), dim3(256), 0, stream>>>(
        xq, wq, xs, scale, bias, out);
  } else {
    bf16_t* wt = (bf16_t*)d_ws;  // 8 MB
    cvt_w_kernel<<<dim3((K_DIM / 64) * (N_DIM / 64)), dim3(256), 0, stream>>>(qw, wt);
    gemm_fb_kernel<<<dim3((M_DIM / 128) * (N_DIM / 128)), dim3(256), 0, stream>>>(
        x, wt, scale, bias, out);
  }
}